// Round 5
// baseline (606.143 us; speedup 1.0000x reference)
//
#include <hip/hip_runtime.h>

// Problem constants
#define NPOS   524288         // 8*16*64*64
#define KCODES 512
#define CDIM   64
#define THW    65536          // 16*64*64
#define NTHR   256            // 4 waves; one position per thread

// out layout (float32): [0, 33554432) quantized BCTHW; [33554432] loss; [33554433, +524288) indices
#define QOUT_N   33554432L
#define LOSS_OFF 33554432L
#define IDX_OFF  33554433L

// ws layout: byte 0: double loss accumulator; byte 256: float ee[512]; byte 4096: float et[64][512]

// ---------- prep: ee[q] = sum_c e[q][c]^2 (numpy pairwise-8) and et[c][q] = emb[q][c] ----------
extern "C" __global__ void vq_prep(const float* __restrict__ emb,
                                   float* __restrict__ ee, float* __restrict__ et) {
    int q = threadIdx.x;               // 512 threads
    const float* er = emb + q * 64;
    float r[8];
    #pragma unroll
    for (int j = 0; j < 8; ++j) { float v = er[j]; r[j] = __fmul_rn(v, v); }
    #pragma unroll
    for (int t = 1; t < 8; ++t)
        #pragma unroll
        for (int j = 0; j < 8; ++j) { float v = er[t * 8 + j]; r[j] = __fadd_rn(r[j], __fmul_rn(v, v)); }
    float s0 = __fadd_rn(__fadd_rn(r[0], r[1]), __fadd_rn(r[2], r[3]));
    float s1 = __fadd_rn(__fadd_rn(r[4], r[5]), __fadd_rn(r[6], r[7]));
    ee[q] = __fadd_rn(s0, s1);
    #pragma unroll
    for (int c = 0; c < 64; ++c) et[c * 512 + q] = er[c];
}

// ---------- main: one position per thread, codebook via scalar path ----------
extern "C" __global__ __launch_bounds__(NTHR)
void vq_main(const float* __restrict__ x, const float* __restrict__ emb,
             float* __restrict__ out, double* __restrict__ lossws,
             const float* __restrict__ eeg, const float* __restrict__ et) {
    const int tid = threadIdx.x;
    const int blk = blockIdx.x;
    const int b   = blk >> 8;                    // 256 blocks per batch element
    const int r   = ((blk & 255) << 8) + tid;    // position within [0, THW)
    const long n  = (long)blk * NTHR + tid;      // global position index

    // ---- load this position's x[0..63] into registers (coalesced dword per c)
    const float* xp = x + (long)b * CDIM * THW + r;
    float a_[64];
    #pragma unroll
    for (int c = 0; c < 64; ++c) a_[c] = xp[(long)c * THW];

    // ---- ff = sum_c a^2, numpy pairwise-8 order
    float ffv;
    {
        float rr[8];
        #pragma unroll
        for (int j = 0; j < 8; ++j) rr[j] = __fmul_rn(a_[j], a_[j]);
        #pragma unroll
        for (int t = 1; t < 8; ++t)
            #pragma unroll
            for (int j = 0; j < 8; ++j)
                rr[j] = __fadd_rn(rr[j], __fmul_rn(a_[t * 8 + j], a_[t * 8 + j]));
        float s0 = __fadd_rn(__fadd_rn(rr[0], rr[1]), __fadd_rn(rr[2], rr[3]));
        float s1 = __fadd_rn(__fadd_rn(rr[4], rr[5]), __fadd_rn(rr[6], rr[7]));
        ffv = __fadd_rn(s0, s1);
    }

    // ---- argmin over all 512 codes, 8 codes per group, e via scalar loads
    float dmin = 1e30f; int kmin = 0;
    #pragma unroll 1
    for (int qg = 0; qg < 64; ++qg) {
        const float* eq = et + qg * 8;           // et[c][qg*8 + k], k contiguous
        float acc[8];
        #pragma unroll
        for (int k = 0; k < 8; ++k) acc[k] = 0.f;
        #pragma unroll
        for (int c = 0; c < 64; ++c) {
            const float* er = eq + c * 512;      // uniform address -> s_load
            float av = a_[c];
            #pragma unroll
            for (int k = 0; k < 8; ++k) acc[k] = __fmaf_rn(av, er[k], acc[k]);
        }
        #pragma unroll
        for (int k = 0; k < 8; ++k) {
            float t1 = __fadd_rn(ffv, eeg[qg * 8 + k]);   // ee uniform -> s_load
            float d  = __fmaf_rn(acc[k], -2.0f, t1);      // == t1 - fl(2*acc), bit-exact
            int q = qg * 8 + k;
            if (d < dmin) { dmin = d; kmin = q; }         // q ascending, strict <
        }
    }

    // ---- indices out (as float)
    out[IDX_OFF + n] = (float)kmin;

    // ---- quantized out (straight-through) + loss partial
    double lacc = 0.0;
    {
        const float* eqr = emb + (long)kmin * 64;         // divergent, L2-hot, 16B-aligned
        float* op = out + (long)b * CDIM * THW + r;
        #pragma unroll
        for (int c4 = 0; c4 < 16; ++c4) {
            float4 ev = *(const float4*)(eqr + c4 * 4);
            float x0 = a_[c4 * 4 + 0], d0 = __fsub_rn(ev.x, x0);
            op[(long)(c4 * 4 + 0) * THW] = __fadd_rn(x0, d0); lacc += (double)__fmul_rn(d0, d0);
            float x1 = a_[c4 * 4 + 1], d1 = __fsub_rn(ev.y, x1);
            op[(long)(c4 * 4 + 1) * THW] = __fadd_rn(x1, d1); lacc += (double)__fmul_rn(d1, d1);
            float x2 = a_[c4 * 4 + 2], d2 = __fsub_rn(ev.z, x2);
            op[(long)(c4 * 4 + 2) * THW] = __fadd_rn(x2, d2); lacc += (double)__fmul_rn(d2, d2);
            float x3 = a_[c4 * 4 + 3], d3 = __fsub_rn(ev.w, x3);
            op[(long)(c4 * 4 + 3) * THW] = __fadd_rn(x3, d3); lacc += (double)__fmul_rn(d3, d3);
        }
    }

    // ---- loss: wave reduce, then 4-wave LDS reduce, one atomic per block
    #pragma unroll
    for (int m = 1; m < 64; m <<= 1) lacc += __shfl_xor(lacc, m, 64);
    __shared__ double wsum[4];
    if ((tid & 63) == 0) wsum[tid >> 6] = lacc;
    __syncthreads();
    if (tid == 0) {
        atomicAdd(lossws, wsum[0] + wsum[1] + wsum[2] + wsum[3]);
    }
}

extern "C" __global__ void vq_finalize(const double* __restrict__ lossws,
                                       float* __restrict__ out) {
    if (threadIdx.x == 0) {
        float m = (float)(lossws[0] / (double)QOUT_N);
        out[LOSS_OFF] = __fadd_rn(m, __fmul_rn(0.025f, m));
    }
}

extern "C" void kernel_launch(void* const* d_in, const int* in_sizes, int n_in,
                              void* d_out, int out_size, void* d_ws, size_t ws_size,
                              hipStream_t stream) {
    const float* x   = (const float*)d_in[0];
    const float* emb = (const float*)d_in[1];
    float* out = (float*)d_out;
    double* loss_ws = (double*)d_ws;
    float* ee_ws = (float*)((char*)d_ws + 256);
    float* et_ws = (float*)((char*)d_ws + 4096);

    hipMemsetAsync(d_ws, 0, sizeof(double), stream);
    hipLaunchKernelGGL(vq_prep, dim3(1), dim3(KCODES), 0, stream, emb, ee_ws, et_ws);

    dim3 grid(NPOS / NTHR);   // 2048
    dim3 block(NTHR);
    hipLaunchKernelGGL(vq_main, grid, block, 0, stream, x, emb, out, loss_ws, ee_ws, et_ws);
    hipLaunchKernelGGL(vq_finalize, dim3(1), dim3(1), 0, stream,
                       (const double*)loss_ws, out);
}

// Round 6
// 592.986 us; speedup vs baseline: 1.0222x; 1.0222x over previous
//
#include <hip/hip_runtime.h>

// Problem constants
#define NPOS   524288         // 8*16*64*64
#define KCODES 512
#define CDIM   64
#define THW    65536          // 16*64*64
#define NTHR   256            // 4 waves; one position per thread

// out layout (float32): [0, 33554432) quantized BCTHW; [33554432] loss; [33554433, +524288) indices
#define QOUT_N   33554432L
#define LOSS_OFF 33554432L
#define IDX_OFF  33554433L

// ws layout: byte 0: double loss accumulator; byte 256: float ee[512]; byte 4096: float etg[64][64][8]
//   etg[qg][c][k] = emb[qg*8+k][c]  (per-code-group contiguous 2 KB)

// ---------- prep: ee[q] (numpy pairwise-8) and grouped-transposed codebook ----------
extern "C" __global__ void vq_prep(const float* __restrict__ emb,
                                   float* __restrict__ ee, float* __restrict__ etg) {
    int q = threadIdx.x;               // 512 threads
    const float* er = emb + q * 64;
    float r[8];
    #pragma unroll
    for (int j = 0; j < 8; ++j) { float v = er[j]; r[j] = __fmul_rn(v, v); }
    #pragma unroll
    for (int t = 1; t < 8; ++t)
        #pragma unroll
        for (int j = 0; j < 8; ++j) { float v = er[t * 8 + j]; r[j] = __fadd_rn(r[j], __fmul_rn(v, v)); }
    float s0 = __fadd_rn(__fadd_rn(r[0], r[1]), __fadd_rn(r[2], r[3]));
    float s1 = __fadd_rn(__fadd_rn(r[4], r[5]), __fadd_rn(r[6], r[7]));
    ee[q] = __fadd_rn(s0, s1);
    int qg = q >> 3, k = q & 7;
    #pragma unroll
    for (int c = 0; c < 64; ++c) etg[(qg * 64 + c) * 8 + k] = er[c];
}

// ---------- main: one position per thread, codebook via scalar path ----------
extern "C" __global__ __launch_bounds__(NTHR, 4)
void vq_main(const float* __restrict__ x, const float* __restrict__ emb,
             float* __restrict__ out, double* __restrict__ lossws,
             const float* __restrict__ eeg, const float* __restrict__ etg) {
    const int tid = threadIdx.x;
    const int blk = blockIdx.x;
    const int b   = blk >> 8;                    // 256 blocks per batch element
    const int r   = ((blk & 255) << 8) + tid;    // position within [0, THW)
    const long n  = (long)blk * NTHR + tid;      // global position index

    // ---- load this position's x[0..63] into registers (coalesced dword per c)
    const float* xp = x + (long)b * CDIM * THW + r;
    float a_[64];
    #pragma unroll
    for (int c = 0; c < 64; ++c) a_[c] = xp[(long)c * THW];

    // ---- ff = sum_c a^2, numpy pairwise-8 order
    float ffv;
    {
        float rr[8];
        #pragma unroll
        for (int j = 0; j < 8; ++j) rr[j] = __fmul_rn(a_[j], a_[j]);
        #pragma unroll
        for (int t = 1; t < 8; ++t)
            #pragma unroll
            for (int j = 0; j < 8; ++j)
                rr[j] = __fadd_rn(rr[j], __fmul_rn(a_[t * 8 + j], a_[t * 8 + j]));
        float s0 = __fadd_rn(__fadd_rn(rr[0], rr[1]), __fadd_rn(rr[2], rr[3]));
        float s1 = __fadd_rn(__fadd_rn(rr[4], rr[5]), __fadd_rn(rr[6], rr[7]));
        ffv = __fadd_rn(s0, s1);
    }

    // ---- argmin over all 512 codes, 8 codes per group, e via scalar loads
    float dmin = 1e30f; int kmin = 0;
    #pragma unroll 1
    for (int qg = 0; qg < 64; ++qg) {
        const float* eq = etg + qg * 512;        // this group's 2 KB, contiguous
        float acc[8];
        // c = 0: start each chain with a multiply (bit-safe vs fma-into-zero:
        // differs only in sign of zero, which cannot change a strict-< argmin)
        {
            float av = a_[0];
            #pragma unroll
            for (int k = 0; k < 8; ++k) acc[k] = __fmul_rn(av, eq[k]);
        }
        #pragma unroll
        for (int c = 1; c < 64; ++c) {
            const float* er = eq + c * 8;        // uniform address -> s_load
            float av = a_[c];
            #pragma unroll
            for (int k = 0; k < 8; ++k) acc[k] = __fmaf_rn(av, er[k], acc[k]);
        }
        #pragma unroll
        for (int k = 0; k < 8; ++k) {
            float t1 = __fadd_rn(ffv, eeg[qg * 8 + k]);   // ee uniform -> s_load
            float d  = __fmaf_rn(acc[k], -2.0f, t1);      // == t1 - fl(2*acc), bit-exact
            int q = qg * 8 + k;
            if (d < dmin) { dmin = d; kmin = q; }         // q ascending, strict <
        }
    }

    // ---- indices out (as float)
    out[IDX_OFF + n] = (float)kmin;

    // ---- quantized out (straight-through) + loss partial
    double lacc = 0.0;
    {
        const float* eqr = emb + (long)kmin * 64;         // divergent, L2-hot, 16B-aligned
        float* op = out + (long)b * CDIM * THW + r;
        #pragma unroll
        for (int c4 = 0; c4 < 16; ++c4) {
            float4 ev = *(const float4*)(eqr + c4 * 4);
            float x0 = a_[c4 * 4 + 0], d0 = __fsub_rn(ev.x, x0);
            op[(long)(c4 * 4 + 0) * THW] = __fadd_rn(x0, d0); lacc += (double)__fmul_rn(d0, d0);
            float x1 = a_[c4 * 4 + 1], d1 = __fsub_rn(ev.y, x1);
            op[(long)(c4 * 4 + 1) * THW] = __fadd_rn(x1, d1); lacc += (double)__fmul_rn(d1, d1);
            float x2 = a_[c4 * 4 + 2], d2 = __fsub_rn(ev.z, x2);
            op[(long)(c4 * 4 + 2) * THW] = __fadd_rn(x2, d2); lacc += (double)__fmul_rn(d2, d2);
            float x3 = a_[c4 * 4 + 3], d3 = __fsub_rn(ev.w, x3);
            op[(long)(c4 * 4 + 3) * THW] = __fadd_rn(x3, d3); lacc += (double)__fmul_rn(d3, d3);
        }
    }

    // ---- loss: wave reduce, then 4-wave LDS reduce, one atomic per block
    #pragma unroll
    for (int m = 1; m < 64; m <<= 1) lacc += __shfl_xor(lacc, m, 64);
    __shared__ double wsum[4];
    if ((tid & 63) == 0) wsum[tid >> 6] = lacc;
    __syncthreads();
    if (tid == 0) {
        atomicAdd(lossws, wsum[0] + wsum[1] + wsum[2] + wsum[3]);
    }
}

extern "C" __global__ void vq_finalize(const double* __restrict__ lossws,
                                       float* __restrict__ out) {
    if (threadIdx.x == 0) {
        float m = (float)(lossws[0] / (double)QOUT_N);
        out[LOSS_OFF] = __fadd_rn(m, __fmul_rn(0.025f, m));
    }
}

extern "C" void kernel_launch(void* const* d_in, const int* in_sizes, int n_in,
                              void* d_out, int out_size, void* d_ws, size_t ws_size,
                              hipStream_t stream) {
    const float* x   = (const float*)d_in[0];
    const float* emb = (const float*)d_in[1];
    float* out = (float*)d_out;
    double* loss_ws = (double*)d_ws;
    float* ee_ws  = (float*)((char*)d_ws + 256);
    float* etg_ws = (float*)((char*)d_ws + 4096);

    hipMemsetAsync(d_ws, 0, sizeof(double), stream);
    hipLaunchKernelGGL(vq_prep, dim3(1), dim3(KCODES), 0, stream, emb, ee_ws, etg_ws);

    dim3 grid(NPOS / NTHR);   // 2048
    dim3 block(NTHR);
    hipLaunchKernelGGL(vq_main, grid, block, 0, stream, x, emb, out, loss_ws, ee_ws, etg_ws);
    hipLaunchKernelGGL(vq_finalize, dim3(1), dim3(1), 0, stream,
                       (const double*)loss_ws, out);
}